// Round 1
// baseline (1129.928 us; speedup 1.0000x reference)
//
#include <hip/hip_runtime.h>

#define NB 8          // batch
#define NC 256        // channels (K)
#define IMG 3600      // 60*60
#define TEMPF 0.2f
#define BM 64
#define BN 64
#define BK 16

// ---------------------------------------------------------------------------
// diag[b,m] = sum_c p1[b,c,pix1(m)] * p2[b,c,pix2(m)]   (un-scaled dot)
// ---------------------------------------------------------------------------
__global__ __launch_bounds__(256)
void diag_kernel(const float* __restrict__ p1, const float* __restrict__ p2,
                 const int* __restrict__ y1, const int* __restrict__ x1,
                 const int* __restrict__ y2, const int* __restrict__ x2,
                 float* __restrict__ diag, int M) {
  int m = blockIdx.x * 256 + threadIdx.x;
  int b = blockIdx.y;
  if (m >= M) return;
  const float* P1 = p1 + (size_t)b * NC * IMG + (y1[m] * 60 + x1[m]);
  const float* P2 = p2 + (size_t)b * NC * IMG + (y2[m] * 60 + x2[m]);
  float s = 0.f;
#pragma unroll 4
  for (int c = 0; c < NC; ++c) s += P1[(size_t)c * IMG] * P2[(size_t)c * IMG];
  diag[b * M + m] = s;
}

// ---------------------------------------------------------------------------
// Fused GEMM + exp + row/col sum-of-exp accumulation.
// dist[b,m,n] = TEMP * sum_c des1[b,c,m]*des2[b,c,n]
// row_sum[b,m] += sum_n exp(dist);  col_sum[b,n] += sum_m exp(dist)
// No max-subtraction needed: |dist| <~ 25 -> exp fits fp32 comfortably.
// ---------------------------------------------------------------------------
__global__ __launch_bounds__(256)
void gemm_lse(const float* __restrict__ p1, const float* __restrict__ p2,
              const int* __restrict__ y1, const int* __restrict__ x1,
              const int* __restrict__ y2, const int* __restrict__ x2,
              float* __restrict__ row_sum, float* __restrict__ col_sum, int M) {
  __shared__ float As[BK][BM];
  __shared__ float Bs[BK][BN];
  __shared__ float rowAcc[BM];
  __shared__ float colAcc[BN];

  const int b  = blockIdx.z;
  const int m0 = blockIdx.x * BM;
  const int n0 = blockIdx.y * BN;
  const int t  = threadIdx.x;
  const int tx = t & 15, ty = t >> 4;

  const float* P1 = p1 + (size_t)b * NC * IMG;
  const float* P2 = p2 + (size_t)b * NC * IMG;

  // Staging addresses are k0-invariant: hoist pixel gather out of K-loop.
  int  pixA[4], pixB[4];
  bool vA[4], vB[4];
#pragma unroll
  for (int i = 0; i < 4; ++i) {
    int idx = t + i * 256;
    int mm  = idx & (BM - 1);
    int gm = m0 + mm, gn = n0 + mm;
    vA[i] = gm < M;
    vB[i] = gn < M;
    pixA[i] = vA[i] ? (y1[gm] * 60 + x1[gm]) : 0;
    pixB[i] = vB[i] ? (y2[gn] * 60 + x2[gn]) : 0;
  }

  float acc[4][4] = {};
  for (int k0 = 0; k0 < NC; k0 += BK) {
    __syncthreads();   // previous compute done before overwriting LDS
#pragma unroll
    for (int i = 0; i < 4; ++i) {
      int idx = t + i * 256;
      int mm  = idx & (BM - 1);
      int kk  = idx >> 6;
      As[kk][mm] = vA[i] ? P1[(size_t)(k0 + kk) * IMG + pixA[i]] : 0.f;
      Bs[kk][mm] = vB[i] ? P2[(size_t)(k0 + kk) * IMG + pixB[i]] : 0.f;
    }
    __syncthreads();
#pragma unroll
    for (int k = 0; k < BK; ++k) {
      float a4[4], b4[4];
#pragma unroll
      for (int i = 0; i < 4; ++i) a4[i] = As[k][ty * 4 + i];
#pragma unroll
      for (int j = 0; j < 4; ++j) b4[j] = Bs[k][tx * 4 + j];
#pragma unroll
      for (int i = 0; i < 4; ++i)
#pragma unroll
        for (int j = 0; j < 4; ++j)
          acc[i][j] += a4[i] * b4[j];
    }
  }

  // ---- epilogue: exp + block-level row/col reduction ----
  if (t < BM)                rowAcc[t] = 0.f;
  else if (t < BM + BN)      colAcc[t - BM] = 0.f;
  __syncthreads();

  bool mv[4], nv[4];
#pragma unroll
  for (int i = 0; i < 4; ++i) mv[i] = (m0 + ty * 4 + i) < M;
#pragma unroll
  for (int j = 0; j < 4; ++j) nv[j] = (n0 + tx * 4 + j) < M;

  float rp[4] = {}, cp[4] = {};
#pragma unroll
  for (int i = 0; i < 4; ++i)
#pragma unroll
    for (int j = 0; j < 4; ++j) {
      float e = (mv[i] && nv[j]) ? __expf(TEMPF * acc[i][j]) : 0.f;
      rp[i] += e;
      cp[j] += e;
    }
#pragma unroll
  for (int i = 0; i < 4; ++i) atomicAdd(&rowAcc[ty * 4 + i], rp[i]);
#pragma unroll
  for (int j = 0; j < 4; ++j) atomicAdd(&colAcc[tx * 4 + j], cp[j]);
  __syncthreads();

  if (t < BM) {
    if (m0 + t < M) atomicAdd(&row_sum[b * M + m0 + t], rowAcc[t]);
  } else if (t < BM + BN) {
    int tt = t - BM;
    if (n0 + tt < M) atomicAdd(&col_sum[b * M + n0 + tt], colAcc[tt]);
  }
}

// ---------------------------------------------------------------------------
// loss = mean( log(row_sum) + log(col_sum) - 2*TEMP*diag )
// ---------------------------------------------------------------------------
__global__ __launch_bounds__(256)
void finalize(const float* __restrict__ row_sum, const float* __restrict__ col_sum,
              const float* __restrict__ diag, float* __restrict__ out, int total) {
  __shared__ float red[256];
  float s = 0.f;
  for (int i = threadIdx.x; i < total; i += 256)
    s += logf(row_sum[i]) + logf(col_sum[i]) - 2.f * TEMPF * diag[i];
  red[threadIdx.x] = s;
  __syncthreads();
  for (int off = 128; off > 0; off >>= 1) {
    if (threadIdx.x < off) red[threadIdx.x] += red[threadIdx.x + off];
    __syncthreads();
  }
  if (threadIdx.x == 0) out[0] = red[0] / (float)total;
}

extern "C" void kernel_launch(void* const* d_in, const int* in_sizes, int n_in,
                              void* d_out, int out_size, void* d_ws, size_t ws_size,
                              hipStream_t stream) {
  const float* p1 = (const float*)d_in[0];
  const float* p2 = (const float*)d_in[1];
  const int* y1 = (const int*)d_in[2];
  const int* x1 = (const int*)d_in[3];
  const int* y2 = (const int*)d_in[4];
  const int* x2 = (const int*)d_in[5];
  const int M = in_sizes[2];   // 3540

  float* ws       = (float*)d_ws;
  float* row_sum  = ws;                 // NB*M
  float* col_sum  = ws + (size_t)NB * M; // NB*M
  float* diagbuf  = ws + (size_t)2 * NB * M;

  // ws is poisoned to 0xAA before every timed launch — zero the accumulators.
  hipMemsetAsync(ws, 0, (size_t)2 * NB * M * sizeof(float), stream);

  dim3 dgrid((M + 255) / 256, NB);
  diag_kernel<<<dgrid, 256, 0, stream>>>(p1, p2, y1, x1, y2, x2, diagbuf, M);

  int nt = (M + BM - 1) / BM;
  dim3 ggrid(nt, nt, NB);
  gemm_lse<<<ggrid, 256, 0, stream>>>(p1, p2, y1, x1, y2, x2, row_sum, col_sum, M);

  finalize<<<1, 256, 0, stream>>>(row_sum, col_sum, diagbuf, (float*)d_out, NB * M);
}

// Round 2
// 302.090 us; speedup vs baseline: 3.7404x; 3.7404x over previous
//
#include <hip/hip_runtime.h>

#define NB 8
#define NC 256
#define IMG 3600
#define TEMPF 0.2f

typedef unsigned short u16;
typedef __bf16 bf16x8 __attribute__((ext_vector_type(8)));
typedef float  f32x4  __attribute__((ext_vector_type(4)));

__device__ __forceinline__ u16 f2bf(float f) {
  unsigned u = __builtin_bit_cast(unsigned, f);
  u += 0x7FFFu + ((u >> 16) & 1u);          // round-to-nearest-even
  return (u16)(u >> 16);
}

__device__ __forceinline__ void gld16(const void* g, void* l) {
  __builtin_amdgcn_global_load_lds(
      (__attribute__((address_space(1))) void*)g,
      (__attribute__((address_space(3))) void*)l, 16, 0, 0);
}

// ---------------------------------------------------------------------------
// Gather + transpose + bf16 cast:  des[b][m][c] = p[b][c][pix(m)]
// m >= M rows zero-filled (masked again in GEMM epilogue).
// ---------------------------------------------------------------------------
__global__ __launch_bounds__(256)
void gather_kernel(const float* __restrict__ p1, const float* __restrict__ p2,
                   const int* __restrict__ y1, const int* __restrict__ x1,
                   const int* __restrict__ y2, const int* __restrict__ x2,
                   u16* __restrict__ des1, u16* __restrict__ des2,
                   int M, int Mp) {
  __shared__ float tile[64][65];           // +1 pad: conflict-free transpose
  const int which = blockIdx.z >> 3;       // 0 -> des1, 1 -> des2
  const int b = blockIdx.z & 7;
  const float* P = (which ? p2 : p1) + (size_t)b * NC * IMG;
  const int* Y = which ? y2 : y1;
  const int* X = which ? x2 : x1;
  u16* D = (which ? des2 : des1) + (size_t)b * Mp * NC;
  const int m0 = blockIdx.x * 64, c0 = blockIdx.y * 64;
  const int t = threadIdx.x;

  const int lm = t & 63, cg = t >> 6;      // load: lane = m, 4 groups of c
  const int m = m0 + lm;
  const bool mv = m < M;
  const int pix = mv ? (Y[m] * 60 + X[m]) : 0;
#pragma unroll
  for (int cc = 0; cc < 16; ++cc) {
    int cl = cg * 16 + cc;
    tile[lm][cl] = mv ? P[(size_t)(c0 + cl) * IMG + pix] : 0.f;
  }
  __syncthreads();
  const int lc = t & 63, mg = t >> 6;      // store: lane = c (coalesced)
#pragma unroll
  for (int mm = 0; mm < 16; ++mm) {
    int ml = mg * 16 + mm;
    D[(size_t)(m0 + ml) * NC + (c0 + lc)] = f2bf(tile[ml][lc]);
  }
}

// ---------------------------------------------------------------------------
// Exact fp32 diagonal: diag[b,m] = sum_c p1[b,c,pix1(m)] * p2[b,c,pix2(m)]
// ---------------------------------------------------------------------------
__global__ __launch_bounds__(256)
void diag_kernel(const float* __restrict__ p1, const float* __restrict__ p2,
                 const int* __restrict__ y1, const int* __restrict__ x1,
                 const int* __restrict__ y2, const int* __restrict__ x2,
                 float* __restrict__ diag, int M) {
  int m = blockIdx.x * 256 + threadIdx.x;
  int b = blockIdx.y;
  if (m >= M) return;
  const float* P1 = p1 + (size_t)b * NC * IMG + (y1[m] * 60 + x1[m]);
  const float* P2 = p2 + (size_t)b * NC * IMG + (y2[m] * 60 + x2[m]);
  float s = 0.f;
#pragma unroll 4
  for (int c = 0; c < NC; ++c) s += P1[(size_t)c * IMG] * P2[(size_t)c * IMG];
  diag[b * M + m] = s;
}

// ---------------------------------------------------------------------------
// MFMA GEMM + fused exp + row/col sum-of-exp.
// dist[b,m,n] = TEMP * <des1[b,m,:], des2[b,n,:]>
// 128x128 tile / block; 4 waves in 2x2; each wave 4x4 of 16x16x32 bf16 MFMA.
// A frag: A[m=lane&15][k=quad*8+j]; C/D: col=lane&15, row=quad*4+reg.
// ---------------------------------------------------------------------------
__global__ __launch_bounds__(256)
void mfma_lse(const u16* __restrict__ des1, const u16* __restrict__ des2,
              float* __restrict__ row_sum, float* __restrict__ col_sum,
              int M, int Mp) {
  __shared__ __align__(16) u16 As[128 * 32];   // [row][k] row-major, 64 B/row
  __shared__ __align__(16) u16 Bs[128 * 32];
  __shared__ float rowAcc[128];
  __shared__ float colAcc[128];

  const int b = blockIdx.z;
  const int m0 = blockIdx.x * 128, n0 = blockIdx.y * 128;
  const int t = threadIdx.x;
  const int w = t >> 6, lane = t & 63;
  const int wm = w >> 1, wn = w & 1;
  const int quad = lane >> 4, l15 = lane & 15;

  const u16* A0 = des1 + ((size_t)b * Mp + m0) * NC;
  const u16* B0 = des2 + ((size_t)b * Mp + n0) * NC;

  // staging: thread t covers rows t/4 and 64+t/4, k-chunk (t&3)*8 (16 B)
  const int srow = t >> 2, skc = (t & 3) * 8;
  const u16* ga0 = A0 + (size_t)srow * NC + skc;
  const u16* ga1 = A0 + (size_t)(64 + srow) * NC + skc;
  const u16* gb0 = B0 + (size_t)srow * NC + skc;
  const u16* gb1 = B0 + (size_t)(64 + srow) * NC + skc;
  u16* la0 = As + t * 8;          // lds byte offset t*16 (wave-contig)
  u16* la1 = As + (256 + t) * 8;
  u16* lb0 = Bs + t * 8;
  u16* lb1 = Bs + (256 + t) * 8;

  f32x4 acc[4][4] = {};

  for (int k0 = 0; k0 < NC; k0 += 32) {
    gld16(ga0 + k0, la0);
    gld16(ga1 + k0, la1);
    gld16(gb0 + k0, lb0);
    gld16(gb1 + k0, lb1);
    __syncthreads();               // vmcnt(0) drain: tiles resident

    bf16x8 af[4], bfr[4];
#pragma unroll
    for (int i = 0; i < 4; ++i)
      af[i] = *(const bf16x8*)&As[(wm * 64 + i * 16 + l15) * 32 + quad * 8];
#pragma unroll
    for (int j = 0; j < 4; ++j)
      bfr[j] = *(const bf16x8*)&Bs[(wn * 64 + j * 16 + l15) * 32 + quad * 8];
#pragma unroll
    for (int i = 0; i < 4; ++i)
#pragma unroll
      for (int j = 0; j < 4; ++j)
        acc[i][j] = __builtin_amdgcn_mfma_f32_16x16x32_bf16(
            af[i], bfr[j], acc[i][j], 0, 0, 0);
    __syncthreads();               // frag reads done before next overwrite
  }

  if (t < 128) rowAcc[t] = 0.f; else colAcc[t - 128] = 0.f;
  __syncthreads();

  // epilogue: exp + reductions. pad rows/cols masked to 0.
  float cp[4] = {0.f, 0.f, 0.f, 0.f};
#pragma unroll
  for (int i = 0; i < 4; ++i) {
    const int rbase = wm * 64 + i * 16 + quad * 4;
#pragma unroll
    for (int r = 0; r < 4; ++r) {
      const int row_l = rbase + r;
      const bool mv = (m0 + row_l) < M;
      float rp = 0.f;
#pragma unroll
      for (int j = 0; j < 4; ++j) {
        const int col_l = wn * 64 + j * 16 + l15;
        const bool nv = (n0 + col_l) < M;
        float e = (mv && nv) ? __expf(TEMPF * acc[i][j][r]) : 0.f;
        rp += e;
        cp[j] += e;
      }
      // sum over the 16 cols held by this quad's lanes
      rp += __shfl_xor(rp, 1);  rp += __shfl_xor(rp, 2);
      rp += __shfl_xor(rp, 4);  rp += __shfl_xor(rp, 8);
      if (l15 == 0) atomicAdd(&rowAcc[row_l], rp);
    }
  }
#pragma unroll
  for (int j = 0; j < 4; ++j) {
    float c = cp[j];
    c += __shfl_xor(c, 16);  c += __shfl_xor(c, 32);   // sum over quads (rows)
    if (quad == 0) atomicAdd(&colAcc[wn * 64 + j * 16 + l15], c);
  }
  __syncthreads();

  if (t < 128) {
    if (m0 + t < M) atomicAdd(&row_sum[b * M + m0 + t], rowAcc[t]);
  } else {
    int tt = t - 128;
    if (n0 + tt < M) atomicAdd(&col_sum[b * M + n0 + tt], colAcc[tt]);
  }
}

// ---------------------------------------------------------------------------
// loss = mean( log(row_sum) + log(col_sum) - 2*TEMP*diag )
// ---------------------------------------------------------------------------
__global__ __launch_bounds__(256)
void finalize(const float* __restrict__ row_sum, const float* __restrict__ col_sum,
              const float* __restrict__ diag, float* __restrict__ out, int total) {
  __shared__ float red[256];
  float s = 0.f;
  for (int i = threadIdx.x; i < total; i += 256)
    s += logf(row_sum[i]) + logf(col_sum[i]) - 2.f * TEMPF * diag[i];
  red[threadIdx.x] = s;
  __syncthreads();
  for (int off = 128; off > 0; off >>= 1) {
    if (threadIdx.x < off) red[threadIdx.x] += red[threadIdx.x + off];
    __syncthreads();
  }
  if (threadIdx.x == 0) out[0] = red[0] / (float)total;
}

extern "C" void kernel_launch(void* const* d_in, const int* in_sizes, int n_in,
                              void* d_out, int out_size, void* d_ws, size_t ws_size,
                              hipStream_t stream) {
  const float* p1 = (const float*)d_in[0];
  const float* p2 = (const float*)d_in[1];
  const int* y1 = (const int*)d_in[2];
  const int* x1 = (const int*)d_in[3];
  const int* y2 = (const int*)d_in[4];
  const int* x2 = (const int*)d_in[5];
  const int M = in_sizes[2];                    // 3540
  const int Mp = ((M + 127) / 128) * 128;       // 3584

  float* row_sum = (float*)d_ws;                // NB*M
  float* col_sum = row_sum + (size_t)NB * M;    // NB*M
  float* diagbuf = col_sum + (size_t)NB * M;    // NB*M
  size_t off = (((size_t)3 * NB * M * sizeof(float)) + 255) & ~(size_t)255;
  u16* des1 = (u16*)((char*)d_ws + off);        // NB*Mp*NC bf16
  u16* des2 = des1 + (size_t)NB * Mp * NC;

  hipMemsetAsync(d_ws, 0, (size_t)2 * NB * M * sizeof(float), stream);

  dim3 ggrid(Mp / 64, NC / 64, 2 * NB);
  gather_kernel<<<ggrid, 256, 0, stream>>>(p1, p2, y1, x1, y2, x2, des1, des2, M, Mp);

  dim3 dgrid((M + 255) / 256, NB);
  diag_kernel<<<dgrid, 256, 0, stream>>>(p1, p2, y1, x1, y2, x2, diagbuf, M);

  dim3 mgrid(Mp / 128, Mp / 128, NB);
  mfma_lse<<<mgrid, 256, 0, stream>>>(des1, des2, row_sum, col_sum, M, Mp);

  finalize<<<1, 256, 0, stream>>>(row_sum, col_sum, diagbuf, (float*)d_out, NB * M);
}